// Round 2
// baseline (2435.560 us; speedup 1.0000x reference)
//
#include <hip/hip_runtime.h>
#include <hip/hip_fp16.h>
#include <math.h>

// Sinkhorn-Knopp, fully register-resident. B=8, n=2048, TAU=1, 20 iters.
//
// P = e .* u_i .* v_j with e = exp(la). Row step: u_i = 1/sum_j e_ij v_j;
// col step: v_j = 1/sum_i e_ij u_i. The whole 64 MB fp16 e-matrix lives in
// VGPRs: 256 blocks x 512 threads, 256 elems/thread = 128 packed-half VGPRs.
// Per iteration: registers -> row sums -> LDS cross-wave col reduce ->
// per-block partial colsum (double-buffered global, no atomics) -> grid
// barrier -> redundant per-block combine (MALL-resident). One barrier/iter.
// e stored as fp16 of exp(la): rel err 2^-11, better than fp16(la) path.

constexpr int Nn    = 2048;
constexpr int Bb    = 8;
constexpr int NBLK  = 256;   // 1 block per CU
constexpr int NTHR  = 512;   // 8 waves
constexpr int ITERS = 20;
constexpr int CGPB  = 32;    // row-chunks (of 64 rows) per batch

using half2v = __attribute__((ext_vector_type(2))) _Float16;

__device__ __forceinline__ float frcp(float x) { return __builtin_amdgcn_rcpf(x); }

__global__ void __launch_bounds__(NTHR, 2) sinkhorn_all(
    const float* __restrict__ la0, float* __restrict__ out,
    float* __restrict__ partial,     // [2][Bb][CGPB][Nn] double-buffered
    unsigned* __restrict__ sy) {     // sy[0]=arrive counter, sy[1]=release flag
  const int tid  = threadIdx.x;
  const int lane = tid & 63;
  const int wave = tid >> 6;
  const int b    = blockIdx.x >> 5;   // batch
  const int cg   = blockIdx.x & 31;   // row-chunk of 64 within batch
  const int r0   = cg * 64 + wave * 8;

  __shared__ float sm[8][Nn];   // 64 KB cross-wave col reduce
  __shared__ float cinv[Nn];    // 8 KB  invS for this batch

  // ---- load + exp -> registers (only read of la0) ----
  half2v e[8][16];   // [row][k*4+p], pair covers cols (k*64+lane)*8 + 2p,+2p+1
  {
    const float* src = la0 + ((size_t)b * Nn + r0) * Nn;
#pragma unroll
    for (int i = 0; i < 8; ++i) {
      const float4* rp = (const float4*)(src + (size_t)i * Nn);
#pragma unroll
      for (int k = 0; k < 4; ++k) {
        const int g = (k * 64 + lane) * 2;
        float4 a = rp[g], c = rp[g + 1];
        e[i][k*4+0] = half2v{(_Float16)__expf(a.x), (_Float16)__expf(a.y)};
        e[i][k*4+1] = half2v{(_Float16)__expf(a.z), (_Float16)__expf(a.w)};
        e[i][k*4+2] = half2v{(_Float16)__expf(c.x), (_Float16)__expf(c.y)};
        e[i][k*4+3] = half2v{(_Float16)__expf(c.z), (_Float16)__expf(c.w)};
      }
    }
  }

  float v[4][8];   // invS for this thread's 32 columns
  float ri[8];     // u for this thread's wave's 8 rows

  // Grid barrier #k (k = 1..ITERS), monotonically counting arrivals.
  auto gridbar = [&](unsigned k) {
    __syncthreads();
    if (tid == 0) {
      __threadfence();  // flush this block's partial stores device-wide
      unsigned got = __hip_atomic_fetch_add(&sy[0], 1u, __ATOMIC_ACQ_REL,
                                            __HIP_MEMORY_SCOPE_AGENT) + 1u;
      if (got == k * (unsigned)NBLK) {
        __hip_atomic_store(&sy[1], k, __ATOMIC_RELEASE, __HIP_MEMORY_SCOPE_AGENT);
      } else {
        while (__hip_atomic_load(&sy[1], __ATOMIC_ACQUIRE,
                                 __HIP_MEMORY_SCOPE_AGENT) < k)
          __builtin_amdgcn_s_sleep(8);
      }
    }
    __syncthreads();
    __threadfence();  // consumer side: refresh caches before partial reads
  };

  // One Sinkhorn iteration: row phase (uses v unless first), col accumulate,
  // cross-wave reduce, write this block's partial colsum.
  auto iteration = [&](bool first, int parity) {
    float acc[4][8];
#pragma unroll
    for (int k = 0; k < 4; ++k)
#pragma unroll
      for (int x = 0; x < 8; ++x) acc[k][x] = 0.f;

#pragma unroll
    for (int i = 0; i < 8; ++i) {
      float s0 = 0.f, s1 = 0.f, s2 = 0.f, s3 = 0.f;  // 4 chains for ILP
#pragma unroll
      for (int k = 0; k < 4; ++k) {
#pragma unroll
        for (int p = 0; p < 4; ++p) {
          float x = (float)e[i][k*4+p][0];
          float y = (float)e[i][k*4+p][1];
          if (first) {
            if (p & 1) { s2 += x; s3 += y; } else { s0 += x; s1 += y; }
          } else {
            if (p & 1) { s2 = fmaf(x, v[k][2*p], s2); s3 = fmaf(y, v[k][2*p+1], s3); }
            else       { s0 = fmaf(x, v[k][2*p], s0); s1 = fmaf(y, v[k][2*p+1], s1); }
          }
        }
      }
      float s = (s0 + s1) + (s2 + s3);
#pragma unroll
      for (int off = 32; off >= 1; off >>= 1) s += __shfl_xor(s, off);
      float r = frcp(s);
      ri[i] = r;
#pragma unroll
      for (int k = 0; k < 4; ++k)
#pragma unroll
        for (int p = 0; p < 4; ++p) {
          acc[k][2*p]   = fmaf((float)e[i][k*4+p][0], r, acc[k][2*p]);
          acc[k][2*p+1] = fmaf((float)e[i][k*4+p][1], r, acc[k][2*p+1]);
        }
    }

    // cross-wave column reduce via LDS
#pragma unroll
    for (int k = 0; k < 4; ++k) {
      float4* d = (float4*)&sm[wave][(k * 64 + lane) * 8];
      d[0] = make_float4(acc[k][0], acc[k][1], acc[k][2], acc[k][3]);
      d[1] = make_float4(acc[k][4], acc[k][5], acc[k][6], acc[k][7]);
    }
    __syncthreads();
    float4 cs = make_float4(0.f, 0.f, 0.f, 0.f);
#pragma unroll
    for (int w = 0; w < 8; ++w) {
      float4 t = *(const float4*)&sm[w][tid * 4];
      cs.x += t.x; cs.y += t.y; cs.z += t.z; cs.w += t.w;
    }
    float* dst = partial + (((size_t)parity * Bb + b) * CGPB + cg) * Nn;
    ((float4*)dst)[tid] = cs;   // coalesced, no contention
  };

  // Combine the 32 per-chunk partials of batch b -> cinv (=1/colsum) -> v regs.
  auto combine = [&](int parity) {
    const float* pb = partial + ((size_t)parity * Bb + b) * CGPB * Nn;
    float4 cs = make_float4(0.f, 0.f, 0.f, 0.f);
#pragma unroll
    for (int c = 0; c < CGPB; ++c) {
      float4 t = ((const float4*)(pb + (size_t)c * Nn))[tid];
      cs.x += t.x; cs.y += t.y; cs.z += t.z; cs.w += t.w;
    }
    ((float4*)&cinv[tid * 4])[0] =
        make_float4(frcp(cs.x), frcp(cs.y), frcp(cs.z), frcp(cs.w));
    __syncthreads();
#pragma unroll
    for (int k = 0; k < 4; ++k) {
      const int g = (k * 64 + lane) * 8;
      float4 a  = *(const float4*)&cinv[g];
      float4 c2 = *(const float4*)&cinv[g + 4];
      v[k][0] = a.x;  v[k][1] = a.y;  v[k][2] = a.z;  v[k][3] = a.w;
      v[k][4] = c2.x; v[k][5] = c2.y; v[k][6] = c2.z; v[k][7] = c2.w;
    }
  };

  iteration(true, 0);
  gridbar(1u);
#pragma unroll 1
  for (int t = 1; t < ITERS; ++t) {
    combine((t - 1) & 1);
    iteration(false, t & 1);
    gridbar((unsigned)(t + 1));
  }
  combine((ITERS - 1) & 1);

  // ---- write out = e * u_i * v_j directly from registers ----
  float* ob = out + ((size_t)b * Nn + r0) * Nn;
#pragma unroll
  for (int i = 0; i < 8; ++i) {
    float4* rp = (float4*)(ob + (size_t)i * Nn);
    const float r = ri[i];
#pragma unroll
    for (int k = 0; k < 4; ++k) {
      const int g = (k * 64 + lane) * 2;
      float4 o0, o1;
      o0.x = (float)e[i][k*4+0][0] * r * v[k][0];
      o0.y = (float)e[i][k*4+0][1] * r * v[k][1];
      o0.z = (float)e[i][k*4+1][0] * r * v[k][2];
      o0.w = (float)e[i][k*4+1][1] * r * v[k][3];
      o1.x = (float)e[i][k*4+2][0] * r * v[k][4];
      o1.y = (float)e[i][k*4+2][1] * r * v[k][5];
      o1.z = (float)e[i][k*4+3][0] * r * v[k][6];
      o1.w = (float)e[i][k*4+3][1] * r * v[k][7];
      rp[g] = o0;
      rp[g + 1] = o1;
    }
  }
}

extern "C" void kernel_launch(void* const* d_in, const int* in_sizes, int n_in,
                              void* d_out, int out_size, void* d_ws, size_t ws_size,
                              hipStream_t stream) {
  (void)in_sizes; (void)n_in; (void)out_size; (void)ws_size;
  const float* la0 = (const float*)d_in[0];
  float* out = (float*)d_out;

  float* partial = (float*)d_ws;                                  // 4 MB
  unsigned* sy = (unsigned*)((char*)d_ws +
                             (size_t)2 * Bb * CGPB * Nn * sizeof(float));
  hipMemsetAsync(sy, 0, 2 * sizeof(unsigned), stream);

  void* args[4] = { (void*)&la0, (void*)&out, (void*)&partial, (void*)&sy };
  hipLaunchCooperativeKernel((const void*)sinkhorn_all, dim3(NBLK), dim3(NTHR),
                             args, 0, stream);
}

// Round 3
// 2170.407 us; speedup vs baseline: 1.1222x; 1.1222x over previous
//
#include <hip/hip_runtime.h>
#include <hip/hip_fp16.h>
#include <math.h>

// Sinkhorn-Knopp, fully register-resident. B=8, n=2048, TAU=1, 20 iters.
//
// P = e .* u_i .* v_j with e = exp(la). Row step: u_i = 1/sum_j e_ij v_j;
// col step: v_j = 1/sum_i e_ij u_i. The 64 MB fp16 e-matrix lives in VGPRs:
// 256 blocks x 512 threads, 256 elems/thread = 128 packed-half VGPRs.
// __launch_bounds__(512,1): 1 block/CU -> 2 waves/SIMD -> ~256 VGPR budget.
// (Round-2 used (512,2) -> 128-VGPR cap -> e spilled to scratch, 1.66 GB of
// scratch FETCH. This is the fix.)
// v kept as fp16 half2 (16 regs) so row sums use v_dot2_f32_f16; fp32 v for
// the final output scale is read from LDS. Per iteration: dot2 row sums ->
// shuffle reduce -> per-col acc -> LDS cross-wave reduce -> per-block partial
// colsum (double-buffered global) -> grid barrier -> redundant combine
// (MALL-resident, 256 KB/block). One barrier per iteration.

constexpr int Nn    = 2048;
constexpr int Bb    = 8;
constexpr int NBLK  = 256;   // 1 block per CU
constexpr int NTHR  = 512;   // 8 waves
constexpr int ITERS = 20;
constexpr int CGPB  = 32;    // row-chunks (of 64 rows) per batch

using half2v = __attribute__((ext_vector_type(2))) _Float16;

__device__ __forceinline__ float frcp(float x) { return __builtin_amdgcn_rcpf(x); }

__global__ void __launch_bounds__(NTHR, 1) sinkhorn_all(
    const float* __restrict__ la0, float* __restrict__ out,
    float* __restrict__ partial,     // [2][Bb][CGPB][Nn] double-buffered
    unsigned* __restrict__ sy) {     // sy[0]=arrive counter, sy[1]=release flag
  const int tid  = threadIdx.x;
  const int lane = tid & 63;
  const int wave = tid >> 6;
  const int b    = blockIdx.x >> 5;   // batch
  const int cg   = blockIdx.x & 31;   // row-chunk of 64 within batch
  const int r0   = cg * 64 + wave * 8;

  __shared__ float sm[8][Nn];   // 64 KB cross-wave col reduce
  __shared__ float cinv[Nn];    // 8 KB  fp32 invS for this batch

  // ---- load + exp -> registers (only read of la0) ----
  half2v e[8][16];   // [row][k*4+p]; pair covers cols (k*64+lane)*8 + 2p,2p+1
  {
    const float* src = la0 + ((size_t)b * Nn + r0) * Nn;
#pragma unroll
    for (int i = 0; i < 8; ++i) {
      const float4* rp = (const float4*)(src + (size_t)i * Nn);
#pragma unroll
      for (int k = 0; k < 4; ++k) {
        const int g = (k * 64 + lane) * 2;
        float4 a = rp[g], c = rp[g + 1];
        e[i][k*4+0] = half2v{(_Float16)__expf(a.x), (_Float16)__expf(a.y)};
        e[i][k*4+1] = half2v{(_Float16)__expf(a.z), (_Float16)__expf(a.w)};
        e[i][k*4+2] = half2v{(_Float16)__expf(c.x), (_Float16)__expf(c.y)};
        e[i][k*4+3] = half2v{(_Float16)__expf(c.z), (_Float16)__expf(c.w)};
      }
    }
  }

  half2v vh[4][4];   // invS (fp16) for this thread's 32 columns; init = 1
#pragma unroll
  for (int k = 0; k < 4; ++k)
#pragma unroll
    for (int p = 0; p < 4; ++p) vh[k][p] = half2v{(_Float16)1.0f, (_Float16)1.0f};
  float ri[8];       // u for this wave's 8 rows (uniform across lanes)

  // Grid barrier #k (k = 1..ITERS), monotonically counting arrivals.
  // (Identical to the round-2 code that passed — do not touch.)
  auto gridbar = [&](unsigned k) {
    __syncthreads();
    if (tid == 0) {
      __threadfence();  // flush this block's partial stores device-wide
      unsigned got = __hip_atomic_fetch_add(&sy[0], 1u, __ATOMIC_ACQ_REL,
                                            __HIP_MEMORY_SCOPE_AGENT) + 1u;
      if (got == k * (unsigned)NBLK) {
        __hip_atomic_store(&sy[1], k, __ATOMIC_RELEASE, __HIP_MEMORY_SCOPE_AGENT);
      } else {
        while (__hip_atomic_load(&sy[1], __ATOMIC_ACQUIRE,
                                 __HIP_MEMORY_SCOPE_AGENT) < k)
          __builtin_amdgcn_s_sleep(8);
      }
    }
    __syncthreads();
    __threadfence();  // consumer side: refresh before partial reads
  };

#pragma unroll 1
  for (int t = 0; t < ITERS; ++t) {
    // ---- row phase: u = 1/(e . v), then col accumulate from registers ----
    float acc[4][8];
#pragma unroll
    for (int k = 0; k < 4; ++k)
#pragma unroll
      for (int x = 0; x < 8; ++x) acc[k][x] = 0.f;

#pragma unroll
    for (int i = 0; i < 8; ++i) {
      float s0 = 0.f, s1 = 0.f, s2 = 0.f, s3 = 0.f;  // 4 chains for ILP
#pragma unroll
      for (int k = 0; k < 4; ++k) {
        s0 = __builtin_amdgcn_fdot2(e[i][k*4+0], vh[k][0], s0, false);
        s1 = __builtin_amdgcn_fdot2(e[i][k*4+1], vh[k][1], s1, false);
        s2 = __builtin_amdgcn_fdot2(e[i][k*4+2], vh[k][2], s2, false);
        s3 = __builtin_amdgcn_fdot2(e[i][k*4+3], vh[k][3], s3, false);
      }
      float s = (s0 + s1) + (s2 + s3);
#pragma unroll
      for (int off = 32; off >= 1; off >>= 1) s += __shfl_xor(s, off);
      const float r = frcp(s);
      ri[i] = r;
#pragma unroll
      for (int k = 0; k < 4; ++k)
#pragma unroll
        for (int p = 0; p < 4; ++p) {
          acc[k][2*p]   = fmaf((float)e[i][k*4+p][0], r, acc[k][2*p]);
          acc[k][2*p+1] = fmaf((float)e[i][k*4+p][1], r, acc[k][2*p+1]);
        }
    }

    // ---- cross-wave column reduce via LDS ----
#pragma unroll
    for (int k = 0; k < 4; ++k) {
      float4* d = (float4*)&sm[wave][(k * 64 + lane) * 8];
      d[0] = make_float4(acc[k][0], acc[k][1], acc[k][2], acc[k][3]);
      d[1] = make_float4(acc[k][4], acc[k][5], acc[k][6], acc[k][7]);
    }
    __syncthreads();
    float4 cs = make_float4(0.f, 0.f, 0.f, 0.f);
#pragma unroll
    for (int w = 0; w < 8; ++w) {
      float4 tt = *(const float4*)&sm[w][tid * 4];
      cs.x += tt.x; cs.y += tt.y; cs.z += tt.z; cs.w += tt.w;
    }
    float* dst = partial + (((size_t)(t & 1) * Bb + b) * CGPB + cg) * Nn;
    ((float4*)dst)[tid] = cs;   // coalesced, no contention

    gridbar((unsigned)(t + 1));

    // ---- combine: colsum over 32 chunk-partials -> cinv (LDS) -> vh regs ----
    const float* pb = partial + ((size_t)(t & 1) * Bb + b) * CGPB * Nn;
    float4 c2 = make_float4(0.f, 0.f, 0.f, 0.f);
#pragma unroll
    for (int c = 0; c < CGPB; ++c) {
      float4 tt = ((const float4*)(pb + (size_t)c * Nn))[tid];
      c2.x += tt.x; c2.y += tt.y; c2.z += tt.z; c2.w += tt.w;
    }
    ((float4*)&cinv[tid * 4])[0] =
        make_float4(frcp(c2.x), frcp(c2.y), frcp(c2.z), frcp(c2.w));
    __syncthreads();
#pragma unroll
    for (int k = 0; k < 4; ++k) {
      const int g = (k * 64 + lane) * 8;
      float4 a  = *(const float4*)&cinv[g];
      float4 c  = *(const float4*)&cinv[g + 4];
      vh[k][0] = half2v{(_Float16)a.x, (_Float16)a.y};
      vh[k][1] = half2v{(_Float16)a.z, (_Float16)a.w};
      vh[k][2] = half2v{(_Float16)c.x, (_Float16)c.y};
      vh[k][3] = half2v{(_Float16)c.z, (_Float16)c.w};
    }
  }

  // ---- write out = e * u_i * v_j (fp32 v from LDS cinv of last combine) ----
  float* ob = out + ((size_t)b * Nn + r0) * Nn;
#pragma unroll
  for (int i = 0; i < 8; ++i) {
    float4* rp = (float4*)(ob + (size_t)i * Nn);
    const float r = ri[i];
#pragma unroll
    for (int k = 0; k < 4; ++k) {
      const int g = (k * 64 + lane) * 2;
      float4 va = *(const float4*)&cinv[(k * 64 + lane) * 8];
      float4 vb = *(const float4*)&cinv[(k * 64 + lane) * 8 + 4];
      float4 o0, o1;
      o0.x = (float)e[i][k*4+0][0] * r * va.x;
      o0.y = (float)e[i][k*4+0][1] * r * va.y;
      o0.z = (float)e[i][k*4+1][0] * r * va.z;
      o0.w = (float)e[i][k*4+1][1] * r * va.w;
      o1.x = (float)e[i][k*4+2][0] * r * vb.x;
      o1.y = (float)e[i][k*4+2][1] * r * vb.y;
      o1.z = (float)e[i][k*4+3][0] * r * vb.z;
      o1.w = (float)e[i][k*4+3][1] * r * vb.w;
      rp[g] = o0;
      rp[g + 1] = o1;
    }
  }
}

extern "C" void kernel_launch(void* const* d_in, const int* in_sizes, int n_in,
                              void* d_out, int out_size, void* d_ws, size_t ws_size,
                              hipStream_t stream) {
  (void)in_sizes; (void)n_in; (void)out_size; (void)ws_size;
  const float* la0 = (const float*)d_in[0];
  float* out = (float*)d_out;

  float* partial = (float*)d_ws;                                  // 4 MB
  unsigned* sy = (unsigned*)((char*)d_ws +
                             (size_t)2 * Bb * CGPB * Nn * sizeof(float));
  hipMemsetAsync(sy, 0, 2 * sizeof(unsigned), stream);

  void* args[4] = { (void*)&la0, (void*)&out, (void*)&partial, (void*)&sy };
  hipLaunchCooperativeKernel((const void*)sinkhorn_all, dim3(NBLK), dim3(NTHR),
                             args, 0, stream);
}

// Round 4
// 2017.537 us; speedup vs baseline: 1.2072x; 1.0758x over previous
//
#include <hip/hip_runtime.h>
#include <hip/hip_fp16.h>
#include <math.h>

// Sinkhorn-Knopp, fully register-resident. B=8, n=2048, TAU=1, 20 iters.
//
// P = e .* u_i .* v_j with e = exp(la). Row step: u_i = 1/sum_j e_ij v_j;
// col step: v_j = 1/sum_i e_ij u_i. The 64 MB fp16 e-matrix lives in VGPRs:
// 256 blocks x 512 threads, 256 elems/thread = 128 packed-half VGPRs.
//
// Register-budget fix (round-3 lesson): LLVM sizes the VGPR budget from
// LDS-implied occupancy. 72 KB LDS -> 2 blocks/CU -> 4 waves/SIMD -> 128-VGPR
// cap -> the e-array spilled (1.27 GB scratch FETCH). Fix: pin
// amdgpu_waves_per_eu(2,2) AND pad LDS to 84 KB so both signals say
// 1 block/CU = 2 waves/SIMD -> 256-VGPR budget. Live state ~200 regs.
//
// Sync: combine of batch b reads only batch b's 32 partials -> 8 independent
// per-batch barriers (32 arrivals each, 256B-padded slots), not one 256-wide.

constexpr int Nn    = 2048;
constexpr int Bb    = 8;
constexpr int NBLK  = 256;   // 1 block per CU
constexpr int NTHR  = 512;   // 8 waves
constexpr int ITERS = 20;
constexpr int CGPB  = 32;    // row-chunks (of 64 rows) per batch
constexpr int SYNC_STRIDE = 64;  // uints per batch slot (256 B)

using half2v = __attribute__((ext_vector_type(2))) _Float16;

__device__ __forceinline__ float frcp(float x) { return __builtin_amdgcn_rcpf(x); }

__global__ void __launch_bounds__(NTHR)
__attribute__((amdgpu_waves_per_eu(2, 2)))
sinkhorn_all(const float* __restrict__ la0, float* __restrict__ out,
             float* __restrict__ partial,   // [2][Bb][CGPB][Nn] double-buffered
             unsigned* __restrict__ sy) {   // per-batch: [b*64]=ctr, [b*64+16]=rel
  const int tid  = threadIdx.x;
  const int lane = tid & 63;
  const int wave = tid >> 6;
  const int b    = blockIdx.x >> 5;   // batch
  const int cg   = blockIdx.x & 31;   // row-chunk of 64 within batch
  const int r0   = cg * 64 + wave * 8;

  __shared__ float sm[8][Nn];     // 64 KB cross-wave col reduce
  __shared__ float cinv[Nn];      // 8 KB  fp32 invS for this batch
  __shared__ float lds_pad[3072]; // 12 KB pad -> 84 KB total: 1 block/CU
  if (tid == 0x7fffffff) lds_pad[0] = 0.f;  // keep pad alive, never executes

  // ---- load + exp -> registers (only read of la0) ----
  half2v e[8][16];   // [row][k*4+p]; pair covers cols (k*64+lane)*8 + 2p,2p+1
  {
    const float* src = la0 + ((size_t)b * Nn + r0) * Nn;
#pragma unroll
    for (int i = 0; i < 8; ++i) {
      const float4* rp = (const float4*)(src + (size_t)i * Nn);
#pragma unroll
      for (int k = 0; k < 4; ++k) {
        const int g = (k * 64 + lane) * 2;
        float4 a = rp[g], c = rp[g + 1];
        e[i][k*4+0] = half2v{(_Float16)__expf(a.x), (_Float16)__expf(a.y)};
        e[i][k*4+1] = half2v{(_Float16)__expf(a.z), (_Float16)__expf(a.w)};
        e[i][k*4+2] = half2v{(_Float16)__expf(c.x), (_Float16)__expf(c.y)};
        e[i][k*4+3] = half2v{(_Float16)__expf(c.z), (_Float16)__expf(c.w)};
      }
    }
  }

  half2v vh[4][4];   // invS (fp16) for this thread's 32 columns; init = 1
#pragma unroll
  for (int k = 0; k < 4; ++k)
#pragma unroll
    for (int p = 0; p < 4; ++p) vh[k][p] = half2v{(_Float16)1.0f, (_Float16)1.0f};
  float ri[8];       // u for this wave's 8 rows (uniform across lanes)

  unsigned* ctr = sy + b * SYNC_STRIDE;
  unsigned* rel = sy + b * SYNC_STRIDE + 16;

  // Per-batch barrier #k (k = 1..ITERS): 32 blocks of batch b.
  auto batchbar = [&](unsigned k) {
    __syncthreads();
    if (tid == 0) {
      __threadfence();  // flush this block's partial stores device-wide
      unsigned got = __hip_atomic_fetch_add(ctr, 1u, __ATOMIC_ACQ_REL,
                                            __HIP_MEMORY_SCOPE_AGENT) + 1u;
      if (got == k * (unsigned)CGPB) {
        __hip_atomic_store(rel, k, __ATOMIC_RELEASE, __HIP_MEMORY_SCOPE_AGENT);
      } else {
        while (__hip_atomic_load(rel, __ATOMIC_ACQUIRE,
                                 __HIP_MEMORY_SCOPE_AGENT) < k)
          __builtin_amdgcn_s_sleep(8);
      }
    }
    __syncthreads();
    __threadfence();  // consumer side: refresh before partial reads
  };

#pragma unroll 1
  for (int t = 0; t < ITERS; ++t) {
    // ---- row phase: u = 1/(e . v), then col accumulate from registers ----
    float acc[4][8];
#pragma unroll
    for (int k = 0; k < 4; ++k)
#pragma unroll
      for (int x = 0; x < 8; ++x) acc[k][x] = 0.f;

#pragma unroll
    for (int i = 0; i < 8; ++i) {
      float s0 = 0.f, s1 = 0.f, s2 = 0.f, s3 = 0.f;  // 4 chains for ILP
#pragma unroll
      for (int k = 0; k < 4; ++k) {
        s0 = __builtin_amdgcn_fdot2(e[i][k*4+0], vh[k][0], s0, false);
        s1 = __builtin_amdgcn_fdot2(e[i][k*4+1], vh[k][1], s1, false);
        s2 = __builtin_amdgcn_fdot2(e[i][k*4+2], vh[k][2], s2, false);
        s3 = __builtin_amdgcn_fdot2(e[i][k*4+3], vh[k][3], s3, false);
      }
      float s = (s0 + s1) + (s2 + s3);
#pragma unroll
      for (int off = 32; off >= 1; off >>= 1) s += __shfl_xor(s, off);
      const float r = frcp(s);
      ri[i] = r;
#pragma unroll
      for (int k = 0; k < 4; ++k)
#pragma unroll
        for (int p = 0; p < 4; ++p) {
          acc[k][2*p]   = fmaf((float)e[i][k*4+p][0], r, acc[k][2*p]);
          acc[k][2*p+1] = fmaf((float)e[i][k*4+p][1], r, acc[k][2*p+1]);
        }
    }

    // ---- cross-wave column reduce via LDS ----
#pragma unroll
    for (int k = 0; k < 4; ++k) {
      float4* d = (float4*)&sm[wave][(k * 64 + lane) * 8];
      d[0] = make_float4(acc[k][0], acc[k][1], acc[k][2], acc[k][3]);
      d[1] = make_float4(acc[k][4], acc[k][5], acc[k][6], acc[k][7]);
    }
    __syncthreads();
    float4 cs = make_float4(0.f, 0.f, 0.f, 0.f);
#pragma unroll
    for (int w = 0; w < 8; ++w) {
      float4 tt = *(const float4*)&sm[w][tid * 4];
      cs.x += tt.x; cs.y += tt.y; cs.z += tt.z; cs.w += tt.w;
    }
    float* dst = partial + (((size_t)(t & 1) * Bb + b) * CGPB + cg) * Nn;
    ((float4*)dst)[tid] = cs;   // coalesced, no contention

    batchbar((unsigned)(t + 1));

    // ---- combine: colsum over 32 chunk-partials -> cinv (LDS) -> vh regs ----
    const float* pb = partial + ((size_t)(t & 1) * Bb + b) * CGPB * Nn;
    float4 c2 = make_float4(0.f, 0.f, 0.f, 0.f);
#pragma unroll
    for (int c = 0; c < CGPB; ++c) {
      float4 tt = ((const float4*)(pb + (size_t)c * Nn))[tid];
      c2.x += tt.x; c2.y += tt.y; c2.z += tt.z; c2.w += tt.w;
    }
    ((float4*)&cinv[tid * 4])[0] =
        make_float4(frcp(c2.x), frcp(c2.y), frcp(c2.z), frcp(c2.w));
    __syncthreads();
#pragma unroll
    for (int k = 0; k < 4; ++k) {
      const int g = (k * 64 + lane) * 8;
      float4 a = *(const float4*)&cinv[g];
      float4 c = *(const float4*)&cinv[g + 4];
      vh[k][0] = half2v{(_Float16)a.x, (_Float16)a.y};
      vh[k][1] = half2v{(_Float16)a.z, (_Float16)a.w};
      vh[k][2] = half2v{(_Float16)c.x, (_Float16)c.y};
      vh[k][3] = half2v{(_Float16)c.z, (_Float16)c.w};
    }
  }

  // ---- write out = e * u_i * v_j (fp32 v from LDS cinv of last combine) ----
  float* ob = out + ((size_t)b * Nn + r0) * Nn;
#pragma unroll
  for (int i = 0; i < 8; ++i) {
    float4* rp = (float4*)(ob + (size_t)i * Nn);
    const float r = ri[i];
#pragma unroll
    for (int k = 0; k < 4; ++k) {
      const int g = (k * 64 + lane) * 2;
      float4 va = *(const float4*)&cinv[(k * 64 + lane) * 8];
      float4 vb = *(const float4*)&cinv[(k * 64 + lane) * 8 + 4];
      float4 o0, o1;
      o0.x = (float)e[i][k*4+0][0] * r * va.x;
      o0.y = (float)e[i][k*4+0][1] * r * va.y;
      o0.z = (float)e[i][k*4+1][0] * r * va.z;
      o0.w = (float)e[i][k*4+1][1] * r * va.w;
      o1.x = (float)e[i][k*4+2][0] * r * vb.x;
      o1.y = (float)e[i][k*4+2][1] * r * vb.y;
      o1.z = (float)e[i][k*4+3][0] * r * vb.z;
      o1.w = (float)e[i][k*4+3][1] * r * vb.w;
      rp[g] = o0;
      rp[g + 1] = o1;
    }
  }
}

extern "C" void kernel_launch(void* const* d_in, const int* in_sizes, int n_in,
                              void* d_out, int out_size, void* d_ws, size_t ws_size,
                              hipStream_t stream) {
  (void)in_sizes; (void)n_in; (void)out_size; (void)ws_size;
  const float* la0 = (const float*)d_in[0];
  float* out = (float*)d_out;

  float* partial = (float*)d_ws;                                  // 4 MB
  unsigned* sy = (unsigned*)((char*)d_ws +
                             (size_t)2 * Bb * CGPB * Nn * sizeof(float));
  hipMemsetAsync(sy, 0, Bb * SYNC_STRIDE * sizeof(unsigned), stream);

  void* args[4] = { (void*)&la0, (void*)&out, (void*)&partial, (void*)&sy };
  hipLaunchCooperativeKernel((const void*)sinkhorn_all, dim3(NBLK), dim3(NTHR),
                             args, 0, stream);
}